// Round 9
// baseline (300.807 us; speedup 1.0000x reference)
//
#include <hip/hip_runtime.h>

#define K_C    500
#define KPAD   512
#define DIM    768
#define NROWS  65536
#define BM     64
#define BK     32
#define NKT    (DIM / BK)      // 24 K-tiles
#define THREADS 512
#define TAU    1.0f
#define RROWS  16              // rescue rows per block

#define BBUF_BYTES 32768       // one B buffer: 4 chunks x 512 centers x 16B

// ---- d_ws layout (bytes) ----
#define WS_CSQ  64
#define WS_LIST 4096
#define WS_CHI  270336

typedef __attribute__((ext_vector_type(8)))  short bf16x8;
typedef __attribute__((ext_vector_type(16))) float f32x16;

__device__ __forceinline__ ushort f2bf(float f) {
    unsigned x = __float_as_uint(f);
    unsigned r = (x + 0x7fffu + ((x >> 16) & 1u)) >> 16;   // RNE
    return (ushort)r;
}

__device__ __forceinline__ uint4 pack_bf8(float4 a, float4 b) {
    float v[8] = {a.x, a.y, a.z, a.w, b.x, b.y, b.z, b.w};
    uint h[8];
    #pragma unroll
    for (int e = 0; e < 8; ++e) h[e] = f2bf(v[e]);
    return make_uint4(h[0] | (h[1] << 16), h[2] | (h[3] << 16),
                      h[4] | (h[5] << 16), h[6] | (h[7] << 16));
}

#define GLOAD16(g, l)                                                        \
    __builtin_amdgcn_global_load_lds(                                        \
        (__attribute__((address_space(1))) void*)(g),                        \
        (__attribute__((address_space(3))) void*)(l), 16, 0, 0)

// ---------------------------------------------------------------------------
// Pre-kernel 1: centers fp32 -> bf16 (RNE), chunk-major tile layout:
// unit u = kt*2048 + j*512 + r holds c[r][kt*32 + j*8 .. +7]. Zero-pads
// rows 500..511 and zeroes the rescue counter.
// ---------------------------------------------------------------------------
__global__ void convert_kernel(const float* __restrict__ c, ushort* __restrict__ chi,
                               int* __restrict__ count) {
    int gid = blockIdx.x * 256 + threadIdx.x;
    if (gid == 0) *count = 0;
    int kt = gid >> 11;
    int u  = gid & 2047;
    int j  = u >> 9;
    int r  = u & 511;
    int kbase = kt * 32 + j * 8;

    ushort h[8];
    if (r < K_C) {
        #pragma unroll
        for (int e = 0; e < 8; ++e) h[e] = f2bf(c[(size_t)r * DIM + kbase + e]);
    } else {
        #pragma unroll
        for (int e = 0; e < 8; ++e) h[e] = 0;
    }
    ushort* ph = chi + (size_t)gid * 8;
    #pragma unroll
    for (int e = 0; e < 8; ++e) ph[e] = h[e];
}

// ---------------------------------------------------------------------------
// Pre-kernel 2: csq[k] = ||c_k||^2 fp32; pads 500..511 with +INF.
// ---------------------------------------------------------------------------
__global__ void csq_kernel(const float* __restrict__ c, float* __restrict__ csq) {
    int wid  = (blockIdx.x * blockDim.x + threadIdx.x) >> 6;
    int lane = threadIdx.x & 63;
    if (wid >= KPAD) return;
    if (wid >= K_C) { if (lane == 0) csq[wid] = INFINITY; return; }
    const float* row = c + (size_t)wid * DIM;
    float s = 0.f;
    #pragma unroll
    for (int j = 0; j < DIM / 64; ++j) {
        float v = row[lane + j * 64];
        s += v * v;
    }
    #pragma unroll
    for (int m = 32; m; m >>= 1) s += __shfl_xor(s, m, 64);
    if (lane == 0) csq[wid] = s;
}

// ---------------------------------------------------------------------------
// Main kernel (round 9): 64 rows x 512 centers, grid 1024, 8 waves = 2m x 4n.
// COUNTED-VMCNT 3-BUFFER PIPELINE (one raw s_barrier per k-tile):
//   iter kt: [A ds_write hv(kt)] -> [s_waitcnt vmcnt(6|4) lgkmcnt(0); s_barrier]
//            -> [issue B(kt+2) gload_lds + x(kt+2) reg loads] -> [8 MFMAs on
//            tile kt] -> [convert x(kt+1) -> hv].
// vmcnt(6) (stager waves, 6 VMEM/iter) / vmcnt(4) (others) retires exactly
// tile kt's loads; tiles kt+1/kt+2 stay in flight across the barrier.
// Buffer-reuse safety: B(t) overwrites buf t%3 last read at compute(t-3),
// which all waves finished before barrier(t-2) -- issue is post-barrier.
// A LDS is double-buffered; x prefetch uses compile-time slot rotation.
// ---------------------------------------------------------------------------
__global__ __launch_bounds__(THREADS, 2) void kmeans_mfma(
        const float* __restrict__ x, const char* __restrict__ ws,
        int* __restrict__ out) {
    __shared__ __align__(16) ushort Bh[3][4][KPAD][8];   // 96 KB
    __shared__ __align__(16) ushort Ah[2][4][BM][8];     // 8 KB
    __shared__ float rv1[4][BM];                         // 1 KB
    __shared__ float rv2[4][BM];                         // 1 KB
    __shared__ int   ridx[4][BM];                        // 1 KB

    const int tid  = threadIdx.x;
    const int w    = tid >> 6;          // wave 0..7
    const int lane = tid & 63;
    const int l31  = lane & 31;
    const int lh   = lane >> 5;
    const int wm   = w >> 2;            // 0..1 row half (32 rows each)
    const int wn   = w & 3;             // 0..3 col quarter (128 cols each)
    const int rowBase = blockIdx.x * BM;

    // A staging (waves 0..3): thread t -> row t>>2 (0..63), k-chunk j = t&3
    const int srow = tid >> 2;
    const int sj   = tid & 3;
    const int sslot = srow ^ (sj << 1);   // bank-conflict-free write slot
    const bool stager = (tid < 256);      // wave-uniform
    const float* xsrc = x + (size_t)(rowBase + srow) * DIM + sj * 8;

    const char* wsChi = ws + WS_CHI;
    const float* csq  = (const float*)(ws + WS_CSQ);
    int* count = (int*)ws;
    int* list  = (int*)(ws + WS_LIST);

    f32x16 acc[4] = {};
    float4 xqa0, xqb0, xqa1, xqb1;   // x prefetch slots (slot = tile&1)
    uint4 hv;                        // converted A for the NEXT top-of-iter write

#define ISSUE_B(T)                                                            \
    {                                                                         \
        const char* sH_ = wsChi + (size_t)(T) * 32768 + w * 4096 + lane * 16; \
        char* dH_ = ((char*)Bh) + ((T) % 3) * BBUF_BYTES + w * 4096;          \
        GLOAD16(sH_ + 0 * 1024, dH_ + 0 * 1024);                              \
        GLOAD16(sH_ + 1 * 1024, dH_ + 1 * 1024);                              \
        GLOAD16(sH_ + 2 * 1024, dH_ + 2 * 1024);                              \
        GLOAD16(sH_ + 3 * 1024, dH_ + 3 * 1024);                              \
    }

    // ---- prologue: B(0), B(1) in flight; x(1) in flight; x(0) converted ----
    ISSUE_B(0);
    ISSUE_B(1);
    if (stager) {
        xqa1 = *reinterpret_cast<const float4*>(xsrc + BK);
        xqb1 = *reinterpret_cast<const float4*>(xsrc + BK + 4);
        float4 a0 = *reinterpret_cast<const float4*>(xsrc);
        float4 b0 = *reinterpret_cast<const float4*>(xsrc + 4);
        hv = pack_bf8(a0, b0);
    }

#define STEP(KT, SI, SC, DOISSUE, DOCONV, VMS, VMNS)                          \
    {                                                                         \
        const int kt_ = (KT);                                                 \
        /* A write: buffer kt&1; prev readers (iter kt-2) done per barrier */ \
        if (stager)                                                           \
            *reinterpret_cast<uint4*>(&Ah[kt_ & 1][sj][sslot][0]) = hv;       \
        /* counted wait + barrier: tile kt landed; kt+1 stays in flight */    \
        if (stager) {                                                         \
            asm volatile("s_waitcnt vmcnt(" VMS ") lgkmcnt(0)\n\t"            \
                         "s_barrier" ::: "memory");                           \
        } else {                                                              \
            asm volatile("s_waitcnt vmcnt(" VMNS ") lgkmcnt(0)\n\t"           \
                         "s_barrier" ::: "memory");                           \
        }                                                                     \
        /* issue tile kt+2 (post-barrier: buf (kt+2)%3's readers are done) */ \
        if (DOISSUE) {                                                        \
            ISSUE_B(kt_ + 2);                                                 \
            if (stager) {                                                     \
                xqa##SI = *reinterpret_cast<const float4*>(                   \
                    xsrc + (kt_ + 2) * BK);                                   \
                xqb##SI = *reinterpret_cast<const float4*>(                   \
                    xsrc + (kt_ + 2) * BK + 4);                               \
            }                                                                 \
        }                                                                     \
        /* compute tile kt: 2 k-steps x 4 MFMAs */                            \
        {                                                                     \
            const ushort* bbase =                                             \
                (const ushort*)(((char*)Bh) + (kt_ % 3) * BBUF_BYTES);        \
            __builtin_amdgcn_s_setprio(1);                                    \
            _Pragma("unroll")                                                 \
            for (int ks = 0; ks < 2; ++ks) {                                  \
                const int j = ks * 2 + lh;                                    \
                const int rsl = (wm * 32 + l31) ^ (j << 1);                   \
                bf16x8 ah0 = *(const bf16x8*)&Ah[kt_ & 1][j][rsl][0];         \
                const ushort* pBh = bbase + ((j * 512) + wn * 128 + l31) * 8; \
                _Pragma("unroll")                                             \
                for (int nf = 0; nf < 4; ++nf) {                              \
                    bf16x8 bh = *(const bf16x8*)(pBh + nf * 32 * 8);          \
                    acc[nf] = __builtin_amdgcn_mfma_f32_32x32x16_bf16(        \
                        ah0, bh, acc[nf], 0, 0, 0);                           \
                }                                                             \
            }                                                                 \
            __builtin_amdgcn_s_setprio(0);                                    \
        }                                                                     \
        /* convert x(kt+1) -> hv for next iter's A write */                   \
        if (DOCONV && stager) hv = pack_bf8(xqa##SC, xqb##SC);                \
    }

    for (int kt = 0; kt < 22; kt += 2) {
        STEP(kt,     0, 1, 1, 1, "6", "4");
        STEP(kt + 1, 1, 0, 1, 1, "6", "4");
    }
    STEP(22, 0, 1, 0, 1, "6", "4");
    STEP(23, 0, 0, 0, 0, "0", "0");

#undef STEP
#undef ISSUE_B

    // ---- epilogue: per-row (best, second, idx) over this wave's 128 cols ----
    float cq[4];
    #pragma unroll
    for (int nf = 0; nf < 4; ++nf) cq[nf] = csq[wn * 128 + nf * 32 + l31];

    #pragma unroll
    for (int reg = 0; reg < 16; ++reg) {
        float v[4]; int col[4];
        #pragma unroll
        for (int nf = 0; nf < 4; ++nf) {
            v[nf]   = fmaf(-2.f, acc[nf][reg], cq[nf]);
            col[nf] = wn * 128 + nf * 32 + l31;
        }
        float paL, paH; int paI;
        if (v[1] < v[0]) { paL = v[1]; paI = col[1]; paH = v[0]; }
        else             { paL = v[0]; paI = col[0]; paH = v[1]; }
        float pbL, pbH; int pbI;
        if (v[3] < v[2]) { pbL = v[3]; pbI = col[3]; pbH = v[2]; }
        else             { pbL = v[2]; pbI = col[2]; pbH = v[3]; }
        float b1, b2; int i1;
        if (pbL < paL) { b1 = pbL; i1 = pbI; b2 = fminf(paL, pbH); }
        else           { b1 = paL; i1 = paI; b2 = fminf(pbL, paH); }
        #pragma unroll
        for (int m = 1; m < 32; m <<= 1) {
            float o1 = __shfl_xor(b1, m, 64);
            float o2 = __shfl_xor(b2, m, 64);
            int   oi = __shfl_xor(i1, m, 64);
            b2 = fminf(fminf(b2, o2), fmaxf(b1, o1));
            if (o1 < b1 || (o1 == b1 && oi < i1)) { b1 = o1; i1 = oi; }
        }
        int row = wm * 32 + (reg & 3) + 8 * (reg >> 2) + 4 * lh;
        if (l31 == 0) { rv1[wn][row] = b1; rv2[wn][row] = b2; ridx[wn][row] = i1; }
    }
    __syncthreads();

    // ---- merge 4 col-quarters per row, write out, flag tight margins ----
    if (tid < BM) {
        float b1 = INFINITY, b2 = INFINITY; int i1 = 0;
        #pragma unroll
        for (int ww = 0; ww < 4; ++ww) {
            float a1 = rv1[ww][tid], a2 = rv2[ww][tid];
            int   ai = ridx[ww][tid];
            b2 = fminf(fminf(b2, a2), fmaxf(b1, a1));
            if (a1 < b1 || (a1 == b1 && ai < i1)) { b1 = a1; i1 = ai; }
        }
        out[rowBase + tid] = i1;
        if (b2 - b1 < TAU) {
            int p = atomicAdd(count, 1);
            list[p] = rowBase + tid;
        }
    }
}

// ---------------------------------------------------------------------------
// Rescue v3 (unchanged): exact fp32, 16 rows/block in LDS; 2 centers/thread
// streamed coalesced; argmin reduced once per block.
// ---------------------------------------------------------------------------
__global__ __launch_bounds__(256) void rescue_kernel(
        const float* __restrict__ x, const float* __restrict__ c,
        const char* __restrict__ ws, int* __restrict__ out) {
    __shared__ __align__(16) float xs[RROWS][DIM];   // 48 KB
    __shared__ float rbv[4][RROWS];
    __shared__ int   rbi[4][RROWS];
    __shared__ int   rows_s[RROWS];
    const float* csq = (const float*)(ws + WS_CSQ);
    const int* list  = (const int*)(ws + WS_LIST);
    const int n = *(const int*)ws;
    const int tid  = threadIdx.x;
    const int w    = tid >> 6;
    const int lane = tid & 63;
    const int k0 = tid * 2;
    const int k1 = tid * 2 + 1;
    const float* c0 = c + (size_t)min(k0, K_C - 1) * DIM;
    const float* c1 = c + (size_t)min(k1, K_C - 1) * DIM;
    const float cq0 = csq[k0];
    const float cq1 = csq[k1];

    for (int g = blockIdx.x; g * RROWS < n; g += gridDim.x) {
        const int base = g * RROWS;
        const int cnt  = min(RROWS, n - base);
        if (tid < RROWS) rows_s[tid] = list[base + min(tid, cnt - 1)];
        __syncthreads();
        #pragma unroll 2
        for (int idx = tid; idx < RROWS * (DIM / 4); idx += 256) {
            int r = idx / (DIM / 4), dc = idx - r * (DIM / 4);
            *reinterpret_cast<float4*>(&xs[r][dc * 4]) =
                *reinterpret_cast<const float4*>(&x[(size_t)rows_s[r] * DIM + dc * 4]);
        }
        __syncthreads();

        float dot0[RROWS], dot1[RROWS];
        #pragma unroll
        for (int r = 0; r < RROWS; ++r) { dot0[r] = 0.f; dot1[r] = 0.f; }

        #pragma unroll 2
        for (int d = 0; d < DIM; d += 4) {
            float4 cv0 = *reinterpret_cast<const float4*>(&c0[d]);
            float4 cv1 = *reinterpret_cast<const float4*>(&c1[d]);
            #pragma unroll
            for (int r = 0; r < RROWS; ++r) {
                float4 xv = *reinterpret_cast<const float4*>(&xs[r][d]);
                dot0[r] = fmaf(xv.x, cv0.x, dot0[r]);
                dot0[r] = fmaf(xv.y, cv0.y, dot0[r]);
                dot0[r] = fmaf(xv.z, cv0.z, dot0[r]);
                dot0[r] = fmaf(xv.w, cv0.w, dot0[r]);
                dot1[r] = fmaf(xv.x, cv1.x, dot1[r]);
                dot1[r] = fmaf(xv.y, cv1.y, dot1[r]);
                dot1[r] = fmaf(xv.z, cv1.z, dot1[r]);
                dot1[r] = fmaf(xv.w, cv1.w, dot1[r]);
            }
        }

        float bv[RROWS]; int bi[RROWS];
        #pragma unroll
        for (int r = 0; r < RROWS; ++r) {
            float v0 = fmaf(-2.f, dot0[r], cq0);
            float v1 = fmaf(-2.f, dot1[r], cq1);
            if (v1 < v0) { bv[r] = v1; bi[r] = k1; }
            else         { bv[r] = v0; bi[r] = k0; }
        }
        #pragma unroll
        for (int m = 1; m < 64; m <<= 1) {
            #pragma unroll
            for (int r = 0; r < RROWS; ++r) {
                float ov = __shfl_xor(bv[r], m, 64);
                int   oi = __shfl_xor(bi[r], m, 64);
                if (ov < bv[r] || (ov == bv[r] && oi < bi[r])) { bv[r] = ov; bi[r] = oi; }
            }
        }
        if (lane == 0) {
            #pragma unroll
            for (int r = 0; r < RROWS; ++r) { rbv[w][r] = bv[r]; rbi[w][r] = bi[r]; }
        }
        __syncthreads();
        if (tid < cnt) {
            float b = rbv[0][tid]; int i = rbi[0][tid];
            #pragma unroll
            for (int ww = 1; ww < 4; ++ww) {
                if (rbv[ww][tid] < b) { b = rbv[ww][tid]; i = rbi[ww][tid]; }
            }
            out[rows_s[tid]] = i;
        }
        __syncthreads();
    }
}

extern "C" void kernel_launch(void* const* d_in, const int* in_sizes, int n_in,
                              void* d_out, int out_size, void* d_ws, size_t ws_size,
                              hipStream_t stream) {
    const float* x = (const float*)d_in[0];
    const float* c = (const float*)d_in[1];
    char* ws = (char*)d_ws;
    int* out = (int*)d_out;

    convert_kernel<<<dim3(192), dim3(256), 0, stream>>>(
        c, (ushort*)(ws + WS_CHI), (int*)ws);
    csq_kernel<<<dim3(128), dim3(256), 0, stream>>>(c, (float*)(ws + WS_CSQ));
    kmeans_mfma<<<dim3(NROWS / BM), dim3(THREADS), 0, stream>>>(x, ws, out);
    rescue_kernel<<<dim3(1024), dim3(256), 0, stream>>>(x, c, ws, out);
}

// Round 10
// 262.316 us; speedup vs baseline: 1.1467x; 1.1467x over previous
//
#include <hip/hip_runtime.h>

#define K_C    500
#define KPAD   512
#define DIM    768
#define NROWS  65536
#define BM     128
#define BK     32
#define NKT    (DIM / BK)      // 24 K-tiles
#define THREADS 512
#define TAU    1.0f
#define RROWS  16              // rescue rows per block

#define BBUF_BYTES 32768       // one B buffer: 4 chunks x 512 centers x 16B
#define ABUF_BYTES 8192        // one A buffer: 4 chunks x 128 rows x 16B

// ---- d_ws layout (bytes) ----
#define WS_CSQ  64
#define WS_LIST 4096
#define WS_CHI  270336

typedef __attribute__((ext_vector_type(8)))  short bf16x8;
typedef __attribute__((ext_vector_type(16))) float f32x16;
typedef __attribute__((ext_vector_type(4)))  float f32x4;

__device__ __forceinline__ ushort f2bf(float f) {
    unsigned x = __float_as_uint(f);
    unsigned r = (x + 0x7fffu + ((x >> 16) & 1u)) >> 16;   // RNE
    return (ushort)r;
}

__device__ __forceinline__ uint4 pack_bf8(f32x4 a, f32x4 b) {
    float v[8] = {a.x, a.y, a.z, a.w, b.x, b.y, b.z, b.w};
    uint h[8];
    #pragma unroll
    for (int e = 0; e < 8; ++e) h[e] = f2bf(v[e]);
    return make_uint4(h[0] | (h[1] << 16), h[2] | (h[3] << 16),
                      h[4] | (h[5] << 16), h[6] | (h[7] << 16));
}

#define GLOAD16(g, l)                                                        \
    __builtin_amdgcn_global_load_lds(                                        \
        (__attribute__((address_space(1))) void*)(g),                        \
        (__attribute__((address_space(3))) void*)(l), 16, 0, 0)

// ---------------------------------------------------------------------------
// Pre-kernel 1: centers fp32 -> bf16 (RNE), chunk-major tile layout:
// unit u = kt*2048 + j*512 + r holds c[r][kt*32 + j*8 .. +7]. Zero-pads
// rows 500..511 and zeroes the rescue counter.
// ---------------------------------------------------------------------------
__global__ void convert_kernel(const float* __restrict__ c, ushort* __restrict__ chi,
                               int* __restrict__ count) {
    int gid = blockIdx.x * 256 + threadIdx.x;
    if (gid == 0) *count = 0;
    int kt = gid >> 11;
    int u  = gid & 2047;
    int j  = u >> 9;
    int r  = u & 511;
    int kbase = kt * 32 + j * 8;

    ushort h[8];
    if (r < K_C) {
        #pragma unroll
        for (int e = 0; e < 8; ++e) h[e] = f2bf(c[(size_t)r * DIM + kbase + e]);
    } else {
        #pragma unroll
        for (int e = 0; e < 8; ++e) h[e] = 0;
    }
    ushort* ph = chi + (size_t)gid * 8;
    #pragma unroll
    for (int e = 0; e < 8; ++e) ph[e] = h[e];
}

// ---------------------------------------------------------------------------
// Pre-kernel 2: csq[k] = ||c_k||^2 fp32; pads 500..511 with +INF.
// ---------------------------------------------------------------------------
__global__ void csq_kernel(const float* __restrict__ c, float* __restrict__ csq) {
    int wid  = (blockIdx.x * blockDim.x + threadIdx.x) >> 6;
    int lane = threadIdx.x & 63;
    if (wid >= KPAD) return;
    if (wid >= K_C) { if (lane == 0) csq[wid] = INFINITY; return; }
    const float* row = c + (size_t)wid * DIM;
    float s = 0.f;
    #pragma unroll
    for (int j = 0; j < DIM / 64; ++j) {
        float v = row[lane + j * 64];
        s += v * v;
    }
    #pragma unroll
    for (int m = 32; m; m >>= 1) s += __shfl_xor(s, m, 64);
    if (lane == 0) csq[wid] = s;
}

// ---------------------------------------------------------------------------
// Main kernel (round 10): 128 rows x 512 centers, 512 blocks, 8 waves=2m x 4n,
// per wave Mf=2 x Nf=4 (acc 128 AGPR). ALL loop VMEM is manually counted:
// B via global_load_lds (3 buffers, 2-deep prefetch), x via inline-asm
// global_load_dwordx4 (2 reg slots) -- the compiler issues NO vmem in the
// loop, so its auto-waitcnt can't drain our pipeline (the r9 serializer).
// Exactly 6 VMEM/wave/iter (4 B + 2 x); the one nontrivial wait vmcnt(6)
// sits after compute (2 iters of slack for tile kt's batch). One barrier/iter.
// ---------------------------------------------------------------------------
__global__ __launch_bounds__(THREADS, 2) void kmeans_mfma(
        const float* __restrict__ x, const char* __restrict__ ws,
        int* __restrict__ out) {
    __shared__ __align__(16) ushort Bh[3][4][KPAD][8];   // 96 KB
    __shared__ __align__(16) ushort Ah[2][4][BM][8];     // 16 KB
    __shared__ float rv1[4][BM];                         // 2 KB
    __shared__ float rv2[4][BM];                         // 2 KB
    __shared__ int   ridx[4][BM];                        // 2 KB

    const int tid  = threadIdx.x;
    const int w    = tid >> 6;          // wave 0..7
    const int lane = tid & 63;
    const int l31  = lane & 31;
    const int lh   = lane >> 5;
    const int wm   = w >> 2;            // 0..1 row half (64 rows each)
    const int wn   = w & 3;             // 0..3 col quarter (128 cols each)
    const int rowBase = blockIdx.x * BM;

    // A staging: thread t -> row t>>2 (0..127), k-chunk j = t&3
    const int srow = tid >> 2;
    const int sj   = tid & 3;
    const int sslot = srow ^ (sj << 1);   // bank-spread write slot
    const float* xsrc = x + (size_t)(rowBase + srow) * DIM + sj * 8;

    const char* wsChi = ws + WS_CHI;
    const float* csq  = (const float*)(ws + WS_CSQ);
    int* count = (int*)ws;
    int* list  = (int*)(ws + WS_LIST);

    f32x16 acc[2][4] = {};
    f32x4 xqa0, xqb0, xqa1, xqb1;   // x prefetch slots: x(T) lives in slot T&1
    uint4 hv;                       // converted A for the next top-of-iter write

#define ISSUE_B(T)                                                            \
    {                                                                         \
        const char* sH_ = wsChi + (size_t)(T) * 32768 + w * 4096 + lane * 16; \
        char* dH_ = ((char*)Bh) + ((T) % 3) * BBUF_BYTES + w * 4096;          \
        GLOAD16(sH_ + 0 * 1024, dH_ + 0 * 1024);                              \
        GLOAD16(sH_ + 1 * 1024, dH_ + 1 * 1024);                              \
        GLOAD16(sH_ + 2 * 1024, dH_ + 2 * 1024);                              \
        GLOAD16(sH_ + 3 * 1024, dH_ + 3 * 1024);                              \
    }

#define ISSUE_X(T, S)                                                         \
    {                                                                         \
        const float* xp_ = xsrc + (T) * BK;                                   \
        asm volatile("global_load_dwordx4 %0, %2, off\n\t"                    \
                     "global_load_dwordx4 %1, %2, off offset:16"              \
                     : "=&v"(xqa##S), "=&v"(xqb##S) : "v"(xp_) : "memory");   \
    }

    // ---- prologue: batches for tiles 0 and 1 in flight; convert x(0) ----
    ISSUE_B(0); ISSUE_X(0, 0);
    ISSUE_B(1); ISSUE_X(1, 1);
    asm volatile("s_waitcnt vmcnt(6)" ::: "memory");   // retire batch 0 (B0+x0)
    __builtin_amdgcn_sched_barrier(0);
    hv = pack_bf8(xqa0, xqb0);

#define STEP(KT, SI, SC, DOISSUE, DOCONV, VMC)                                \
    {                                                                         \
        const int kt_ = (KT);                                                 \
        /* A write for tile kt (hv converted last iter) */                    \
        *reinterpret_cast<uint4*>(&Ah[kt_ & 1][sj][sslot][0]) = hv;           \
        /* barrier: B(kt) already retired by last iter's convert-wait */      \
        asm volatile("s_waitcnt vmcnt(6) lgkmcnt(0)\n\t"                      \
                     "s_barrier" ::: "memory");                               \
        /* issue batch for tile kt+2 (buf (kt+2)%3: readers done @ kt-1) */   \
        if (DOISSUE) { ISSUE_B(kt_ + 2); ISSUE_X(kt_ + 2, SI); }              \
        /* compute tile kt: 2 k-steps x 8 MFMAs */                            \
        {                                                                     \
            const ushort* bbase =                                             \
                (const ushort*)(((const char*)Bh) + (kt_ % 3) * BBUF_BYTES);  \
            const ushort* abase =                                             \
                (const ushort*)(((const char*)Ah) + (kt_ & 1) * ABUF_BYTES);  \
            __builtin_amdgcn_s_setprio(1);                                    \
            _Pragma("unroll")                                                 \
            for (int ks = 0; ks < 2; ++ks) {                                  \
                const int j = ks * 2 + lh;                                    \
                const int rsl = l31 ^ (j << 1);                               \
                const ushort* pA = abase + ((j * BM) + wm * 64 + rsl) * 8;    \
                bf16x8 ah0 = *(const bf16x8*)pA;                              \
                bf16x8 ah1 = *(const bf16x8*)(pA + 32 * 8);                   \
                const ushort* pB = bbase + ((j * 512) + wn * 128 + l31) * 8;  \
                _Pragma("unroll")                                             \
                for (int nf = 0; nf < 4; ++nf) {                              \
                    bf16x8 bh = *(const bf16x8*)(pB + nf * 32 * 8);           \
                    acc[0][nf] = __builtin_amdgcn_mfma_f32_32x32x16_bf16(     \
                        ah0, bh, acc[0][nf], 0, 0, 0);                        \
                    acc[1][nf] = __builtin_amdgcn_mfma_f32_32x32x16_bf16(     \
                        ah1, bh, acc[1][nf], 0, 0, 0);                        \
                }                                                             \
            }                                                                 \
            __builtin_amdgcn_s_setprio(0);                                    \
        }                                                                     \
        /* convert x(kt+1): retire batch(kt-1) = {B(kt+1), x(kt+1)} */        \
        if (DOCONV) {                                                         \
            asm volatile("s_waitcnt vmcnt(" VMC ")" ::: "memory");            \
            __builtin_amdgcn_sched_barrier(0);                                \
            hv = pack_bf8(xqa##SC, xqb##SC);                                  \
        }                                                                     \
    }

    for (int kt = 0; kt < 22; kt += 2) {
        STEP(kt,     0, 1, 1, 1, "6");
        STEP(kt + 1, 1, 0, 1, 1, "6");
    }
    STEP(22, 0, 1, 0, 1, "0");
    STEP(23, 0, 0, 0, 0, "0");

#undef STEP
#undef ISSUE_B
#undef ISSUE_X

    // ---- epilogue: per-row (best, second, idx) over this wave's 128 cols ----
    float cq[4];
    #pragma unroll
    for (int nf = 0; nf < 4; ++nf) cq[nf] = csq[wn * 128 + nf * 32 + l31];

    #pragma unroll
    for (int mf = 0; mf < 2; ++mf) {
        #pragma unroll
        for (int reg = 0; reg < 16; ++reg) {
            float v[4]; int col[4];
            #pragma unroll
            for (int nf = 0; nf < 4; ++nf) {
                v[nf]   = fmaf(-2.f, acc[mf][nf][reg], cq[nf]);
                col[nf] = wn * 128 + nf * 32 + l31;
            }
            float paL, paH; int paI;
            if (v[1] < v[0]) { paL = v[1]; paI = col[1]; paH = v[0]; }
            else             { paL = v[0]; paI = col[0]; paH = v[1]; }
            float pbL, pbH; int pbI;
            if (v[3] < v[2]) { pbL = v[3]; pbI = col[3]; pbH = v[2]; }
            else             { pbL = v[2]; pbI = col[2]; pbH = v[3]; }
            float b1, b2; int i1;
            if (pbL < paL) { b1 = pbL; i1 = pbI; b2 = fminf(paL, pbH); }
            else           { b1 = paL; i1 = paI; b2 = fminf(pbL, paH); }
            #pragma unroll
            for (int m = 1; m < 32; m <<= 1) {
                float o1 = __shfl_xor(b1, m, 64);
                float o2 = __shfl_xor(b2, m, 64);
                int   oi = __shfl_xor(i1, m, 64);
                b2 = fminf(fminf(b2, o2), fmaxf(b1, o1));
                if (o1 < b1 || (o1 == b1 && oi < i1)) { b1 = o1; i1 = oi; }
            }
            int row = wm * 64 + mf * 32 + (reg & 3) + 8 * (reg >> 2) + 4 * lh;
            if (l31 == 0) { rv1[wn][row] = b1; rv2[wn][row] = b2; ridx[wn][row] = i1; }
        }
    }
    __syncthreads();

    // ---- merge 4 col-quarters per row, write out, flag tight margins ----
    if (tid < BM) {
        float b1 = INFINITY, b2 = INFINITY; int i1 = 0;
        #pragma unroll
        for (int ww = 0; ww < 4; ++ww) {
            float a1 = rv1[ww][tid], a2 = rv2[ww][tid];
            int   ai = ridx[ww][tid];
            b2 = fminf(fminf(b2, a2), fmaxf(b1, a1));
            if (a1 < b1 || (a1 == b1 && ai < i1)) { b1 = a1; i1 = ai; }
        }
        out[rowBase + tid] = i1;
        if (b2 - b1 < TAU) {
            int p = atomicAdd(count, 1);
            list[p] = rowBase + tid;
        }
    }
}

// ---------------------------------------------------------------------------
// Rescue v3 (unchanged): exact fp32, 16 rows/block in LDS; 2 centers/thread
// streamed coalesced; argmin reduced once per block.
// ---------------------------------------------------------------------------
__global__ __launch_bounds__(256) void rescue_kernel(
        const float* __restrict__ x, const float* __restrict__ c,
        const char* __restrict__ ws, int* __restrict__ out) {
    __shared__ __align__(16) float xs[RROWS][DIM];   // 48 KB
    __shared__ float rbv[4][RROWS];
    __shared__ int   rbi[4][RROWS];
    __shared__ int   rows_s[RROWS];
    const float* csq = (const float*)(ws + WS_CSQ);
    const int* list  = (const int*)(ws + WS_LIST);
    const int n = *(const int*)ws;
    const int tid  = threadIdx.x;
    const int w    = tid >> 6;
    const int lane = tid & 63;
    const int k0 = tid * 2;
    const int k1 = tid * 2 + 1;
    const float* c0 = c + (size_t)min(k0, K_C - 1) * DIM;
    const float* c1 = c + (size_t)min(k1, K_C - 1) * DIM;
    const float cq0 = csq[k0];
    const float cq1 = csq[k1];

    for (int g = blockIdx.x; g * RROWS < n; g += gridDim.x) {
        const int base = g * RROWS;
        const int cnt  = min(RROWS, n - base);
        if (tid < RROWS) rows_s[tid] = list[base + min(tid, cnt - 1)];
        __syncthreads();
        #pragma unroll 2
        for (int idx = tid; idx < RROWS * (DIM / 4); idx += 256) {
            int r = idx / (DIM / 4), dc = idx - r * (DIM / 4);
            *reinterpret_cast<float4*>(&xs[r][dc * 4]) =
                *reinterpret_cast<const float4*>(&x[(size_t)rows_s[r] * DIM + dc * 4]);
        }
        __syncthreads();

        float dot0[RROWS], dot1[RROWS];
        #pragma unroll
        for (int r = 0; r < RROWS; ++r) { dot0[r] = 0.f; dot1[r] = 0.f; }

        #pragma unroll 2
        for (int d = 0; d < DIM; d += 4) {
            float4 cv0 = *reinterpret_cast<const float4*>(&c0[d]);
            float4 cv1 = *reinterpret_cast<const float4*>(&c1[d]);
            #pragma unroll
            for (int r = 0; r < RROWS; ++r) {
                float4 xv = *reinterpret_cast<const float4*>(&xs[r][d]);
                dot0[r] = fmaf(xv.x, cv0.x, dot0[r]);
                dot0[r] = fmaf(xv.y, cv0.y, dot0[r]);
                dot0[r] = fmaf(xv.z, cv0.z, dot0[r]);
                dot0[r] = fmaf(xv.w, cv0.w, dot0[r]);
                dot1[r] = fmaf(xv.x, cv1.x, dot1[r]);
                dot1[r] = fmaf(xv.y, cv1.y, dot1[r]);
                dot1[r] = fmaf(xv.z, cv1.z, dot1[r]);
                dot1[r] = fmaf(xv.w, cv1.w, dot1[r]);
            }
        }

        float bv[RROWS]; int bi[RROWS];
        #pragma unroll
        for (int r = 0; r < RROWS; ++r) {
            float v0 = fmaf(-2.f, dot0[r], cq0);
            float v1 = fmaf(-2.f, dot1[r], cq1);
            if (v1 < v0) { bv[r] = v1; bi[r] = k1; }
            else         { bv[r] = v0; bi[r] = k0; }
        }
        #pragma unroll
        for (int m = 1; m < 64; m <<= 1) {
            #pragma unroll
            for (int r = 0; r < RROWS; ++r) {
                float ov = __shfl_xor(bv[r], m, 64);
                int   oi = __shfl_xor(bi[r], m, 64);
                if (ov < bv[r] || (ov == bv[r] && oi < bi[r])) { bv[r] = ov; bi[r] = oi; }
            }
        }
        if (lane == 0) {
            #pragma unroll
            for (int r = 0; r < RROWS; ++r) { rbv[w][r] = bv[r]; rbi[w][r] = bi[r]; }
        }
        __syncthreads();
        if (tid < cnt) {
            float b = rbv[0][tid]; int i = rbi[0][tid];
            #pragma unroll
            for (int ww = 1; ww < 4; ++ww) {
                if (rbv[ww][tid] < b) { b = rbv[ww][tid]; i = rbi[ww][tid]; }
            }
            out[rows_s[tid]] = i;
        }
        __syncthreads();
    }
}

extern "C" void kernel_launch(void* const* d_in, const int* in_sizes, int n_in,
                              void* d_out, int out_size, void* d_ws, size_t ws_size,
                              hipStream_t stream) {
    const float* x = (const float*)d_in[0];
    const float* c = (const float*)d_in[1];
    char* ws = (char*)d_ws;
    int* out = (int*)d_out;

    convert_kernel<<<dim3(192), dim3(256), 0, stream>>>(
        c, (ushort*)(ws + WS_CHI), (int*)ws);
    csq_kernel<<<dim3(128), dim3(256), 0, stream>>>(c, (float*)(ws + WS_CSQ));
    kmeans_mfma<<<dim3(NROWS / BM), dim3(THREADS), 0, stream>>>(x, ws, out);
    rescue_kernel<<<dim3(1024), dim3(256), 0, stream>>>(x, c, ws, out);
}